// Round 4
// baseline (898.816 us; speedup 1.0000x reference)
//
#include <hip/hip_runtime.h>
#include <hip/hip_cooperative_groups.h>

namespace cg = cooperative_groups;

// ---------------------------------------------------------------------------
// TopKPooling (PyG-style) on MI355X.
// score = tanh((x @ w) / ||w||)  [XLA EmitTanh f32 replica — DO NOT TOUCH,
//                                 bit-exactness validated in round 1]
// One cooperative kernel: score + 4-pass stable LSD radix sort (u64 packed
// key|idx, ballot-ranked scatter) + select. Then one persistent edge kernel
// with the full 122KB selected-bitmap in LDS.
// ---------------------------------------------------------------------------

#define N_NODES 1000000
#define N_EDGES 16000000
#define K_SEL   500000

typedef int      v4i __attribute__((ext_vector_type(4)));
typedef float    v4f __attribute__((ext_vector_type(4)));
typedef unsigned v4u __attribute__((ext_vector_type(4)));
typedef unsigned long long u64;

static constexpr int NDIG     = 256;
static constexpr int STHREADS = 256;                 // 4 waves
static constexpr int SIPT     = 8;
static constexpr int SCHUNK   = STHREADS * SIPT;     // 2048
static constexpr int NB       = (N_NODES + SCHUNK - 1) / SCHUNK;  // 489
static constexpr int NWAVE    = STHREADS / 64;

static constexpr int EB_THREADS = 1024;
static constexpr int EB_EDGES   = EB_THREADS * 8;    // 8192
static constexpr int NCHUNK     = (N_EDGES + EB_EDGES - 1) / EB_EDGES;  // 1954
static constexpr int NODE_SPLIT = 524288;            // fallback two-phase split
static constexpr int BM_WORDS   = (N_NODES + 31) / 32;   // 31250
static constexpr int BM_W0      = NODE_SPLIT / 32;       // 16384 (64 KiB)
static constexpr int BM_W1      = BM_WORDS - BM_W0;      // 14866
static constexpr int BM_ALLOC   = 31264;                 // padded to x4

// --- XLA EmitTanh f32 replica (elemental_ir_emitter). No FMA contraction. ---
__device__ __forceinline__ float tanh_xla(float x) {
  const float kCutoff = 0.0004f;
  const float kClamp  = 7.90531110763549805f;
  float ax = fabsf(x);
  float xc = fminf(fmaxf(x, -kClamp), kClamp);
  float x2 = __fmul_rn(xc, xc);
  float p = -2.76076847742355e-16f;
  p = __fadd_rn(__fmul_rn(p, x2),  2.00018790482477e-13f);
  p = __fadd_rn(__fmul_rn(p, x2), -8.60467152213735e-11f);
  p = __fadd_rn(__fmul_rn(p, x2),  5.12229709037114e-08f);
  p = __fadd_rn(__fmul_rn(p, x2),  1.48572235717979e-05f);
  p = __fadd_rn(__fmul_rn(p, x2),  6.37261928875436e-04f);
  p = __fadd_rn(__fmul_rn(p, x2),  4.89352455891786e-03f);
  float num = __fmul_rn(xc, p);
  float q = 1.19825839466702e-06f;
  q = __fadd_rn(__fmul_rn(q, x2), 1.18534705686654e-04f);
  q = __fadd_rn(__fmul_rn(q, x2), 2.26843463243900e-03f);
  q = __fadd_rn(__fmul_rn(q, x2), 4.89352518554385e-03f);
  float r = __fdiv_rn(num, q);
  return (ax < kCutoff) ? x : r;
}

// ======================= cooperative fused kernel ==========================
__global__ __launch_bounds__(STHREADS) void topk_coop(
    const float* __restrict__ x, const float* __restrict__ w,
    float* __restrict__ score, u64* __restrict__ kp0, u64* __restrict__ kp1,
    unsigned* __restrict__ histDM, unsigned* __restrict__ rowsum,
    int* __restrict__ ni, unsigned* __restrict__ bm, float* __restrict__ xout) {
  cg::grid_group grid = cg::this_grid();
  __shared__ unsigned short whist[SIPT][NWAVE][NDIG];  // 16 KiB
  __shared__ unsigned goff[NDIG];
  __shared__ unsigned bexcl[NDIG];
  __shared__ unsigned scanbuf[NDIG];
  __shared__ u64 lkp[SCHUNK];                          // 16 KiB
  const int t = threadIdx.x, b = blockIdx.x;
  const int wave = t >> 6, lane = t & 63;
  const int base = b * SCHUNK;

  // ---- Phase A: init ni/bm + score + keys + pass-0 histogram ----
  goff[t] = 0;
  __syncthreads();
  {
    float w0 = w[0], w1 = w[1], w2 = w[2];
    float nrm = __fsqrt_rn(__fadd_rn(__fadd_rn(__fmul_rn(w0, w0), __fmul_rn(w1, w1)),
                                     __fmul_rn(w2, w2)));
#pragma unroll
    for (int s = 0; s < SIPT; ++s) {
      int i = base + s * STHREADS + t;
      if (i < N_NODES) {
        ni[i] = -1;
        float dot = __fadd_rn(__fadd_rn(__fmul_rn(x[3*i+0], w0), __fmul_rn(x[3*i+1], w1)),
                              __fmul_rn(x[3*i+2], w2));
        float z = __fdiv_rn(dot, nrm);
        float sc = tanh_xla(z);
        score[i] = sc;
        unsigned u = __float_as_uint(sc);
        if (u == 0x80000000u) u = 0u;                    // -0 == +0
        u = (u & 0x80000000u) ? ~u : (u | 0x80000000u);  // ascending map
        unsigned key = ~u;                               // descending score
        kp0[i] = ((u64)key << 32) | (unsigned)i;
        atomicAdd(&goff[key & 255u], 1u);
      }
    }
    if (t < 64) { int wi = b * 64 + t; if (wi < BM_ALLOC) bm[wi] = 0u; }
  }
  __syncthreads();
  histDM[t * NB + b] = goff[t];
  grid.sync();

  for (int pass = 0; pass < 4; ++pass) {
    const u64* kin = (pass & 1) ? kp1 : kp0;
    u64* kout      = (pass & 1) ? kp0 : kp1;
    const int sh = 32 + 8 * pass;

    // ---- Phase B: exclusive scan of each digit row (blocks 0..255) ----
    if (b < NDIG) {
      unsigned v0 = (2*t     < NB) ? histDM[b*NB + 2*t]     : 0u;
      unsigned v1 = (2*t + 1 < NB) ? histDM[b*NB + 2*t + 1] : 0u;
      unsigned ps = v0 + v1;
      scanbuf[t] = ps;
      __syncthreads();
#pragma unroll
      for (int o = 1; o < NDIG; o <<= 1) {
        unsigned add = (t >= o) ? scanbuf[t - o] : 0u;
        __syncthreads();
        scanbuf[t] += add;
        __syncthreads();
      }
      unsigned excl = scanbuf[t] - ps;
      if (2*t     < NB) histDM[b*NB + 2*t]     = excl;
      if (2*t + 1 < NB) histDM[b*NB + 2*t + 1] = excl + v0;
      if (t == NDIG - 1) rowsum[b] = scanbuf[t];
    }
    grid.sync();

    // ---- Phase C: stable ballot-ranked scatter ----
    {
      for (int j = t; j < SIPT * NWAVE * NDIG; j += STHREADS)
        ((unsigned short*)whist)[j] = 0;
      unsigned rs = rowsum[t];
      scanbuf[t] = rs;
      __syncthreads();
#pragma unroll
      for (int o = 1; o < NDIG; o <<= 1) {
        unsigned add = (t >= o) ? scanbuf[t - o] : 0u;
        __syncthreads();
        scanbuf[t] += add;
        __syncthreads();
      }
      goff[t] = (scanbuf[t] - rs) + histDM[t * NB + b];
      __syncthreads();

      u64 k[SIPT];
      unsigned dg[SIPT], lr[SIPT];
      bool val[SIPT];
#pragma unroll
      for (int s = 0; s < SIPT; ++s) {
        int i = base + s * STHREADS + t;
        val[s] = (i < N_NODES);
        k[s] = val[s] ? kin[i] : 0ull;
        dg[s] = (unsigned)(k[s] >> sh) & 255u;
      }
#pragma unroll
      for (int s = 0; s < SIPT; ++s) {
        unsigned long long m = ~0ull;
#pragma unroll
        for (int bb = 0; bb < 8; ++bb) {
          unsigned long long vote = __ballot((dg[s] >> bb) & 1u);
          m &= ((dg[s] >> bb) & 1u) ? vote : ~vote;
        }
        m &= __ballot(val[s]);
        lr[s] = (unsigned)__popcll(m & ((1ull << lane) - 1ull));
        if (val[s] && lr[s] == 0)
          whist[s][wave][dg[s]] = (unsigned short)__popcll(m);
      }
      __syncthreads();
      unsigned run = 0;
#pragma unroll
      for (int s = 0; s < SIPT; ++s)
#pragma unroll
        for (int wv = 0; wv < NWAVE; ++wv) {
          unsigned c = whist[s][wv][t];
          whist[s][wv][t] = (unsigned short)run;
          run += c;
        }
      scanbuf[t] = run;
      __syncthreads();
#pragma unroll
      for (int o = 1; o < NDIG; o <<= 1) {
        unsigned add = (t >= o) ? scanbuf[t - o] : 0u;
        __syncthreads();
        scanbuf[t] += add;
        __syncthreads();
      }
      bexcl[t] = scanbuf[t] - run;
      __syncthreads();
#pragma unroll
      for (int s = 0; s < SIPT; ++s)
        if (val[s]) {
          unsigned lp = bexcl[dg[s]] + (unsigned)whist[s][wave][dg[s]] + lr[s];
          lkp[lp] = k[s];
        }
      __syncthreads();
      int nvalid = min(N_NODES - base, SCHUNK);
#pragma unroll
      for (int s = 0; s < SIPT; ++s) {
        int j = s * STHREADS + t;
        if (j < nvalid) {
          u64 kk = lkp[j];
          unsigned d = (unsigned)(kk >> sh) & 255u;
          kout[goff[d] + ((unsigned)j - bexcl[d])] = kk;
        }
      }
    }
    grid.sync();

    // ---- Phase A': histogram for next pass ----
    if (pass < 3) {
      goff[t] = 0;
      __syncthreads();
      const int sh2 = sh + 8;
#pragma unroll
      for (int s = 0; s < SIPT; ++s) {
        int i = base + s * STHREADS + t;
        if (i < N_NODES) atomicAdd(&goff[(unsigned)(kout[i] >> sh2) & 255u], 1u);
      }
      __syncthreads();
      histDM[t * NB + b] = goff[t];
      grid.sync();
    }
  }

  // ---- Phase S: select (sorted result is in kp0) ----
#pragma unroll
  for (int s = 0; s < 4; ++s) {
    int i = b * 1024 + s * STHREADS + t;
    if (i < K_SEL) {
      u64 kk = kp0[i];
      int pidx = (int)(unsigned)(kk & 0xFFFFFFFFull);
      ni[pidx] = i;
      atomicOr(&bm[pidx >> 5], 1u << (pidx & 31));
      float sc = score[pidx];
      xout[3*i+0] = __fmul_rn(x[3*pidx+0], sc);
      xout[3*i+1] = __fmul_rn(x[3*pidx+1], sc);
      xout[3*i+2] = __fmul_rn(x[3*pidx+2], sc);
    }
  }
}

// ==================== fallback multi-kernel sort path ======================
__global__ void score_kernel(const float* __restrict__ x, const float* __restrict__ w,
                             float* __restrict__ score, u64* __restrict__ kp, int n) {
  int i = blockIdx.x * blockDim.x + threadIdx.x;
  if (i >= n) return;
  float w0 = w[0], w1 = w[1], w2 = w[2];
  float nrm = __fsqrt_rn(__fadd_rn(__fadd_rn(__fmul_rn(w0, w0), __fmul_rn(w1, w1)),
                                   __fmul_rn(w2, w2)));
  float dot = __fadd_rn(__fadd_rn(__fmul_rn(x[3*i+0], w0), __fmul_rn(x[3*i+1], w1)),
                        __fmul_rn(x[3*i+2], w2));
  float z = __fdiv_rn(dot, nrm);
  float s = tanh_xla(z);
  score[i] = s;
  unsigned u = __float_as_uint(s);
  if (u == 0x80000000u) u = 0u;
  u = (u & 0x80000000u) ? ~u : (u | 0x80000000u);
  kp[i] = ((u64)(~u) << 32) | (unsigned)i;
}

__global__ void radix_hist(const u64* __restrict__ kp, int n,
                           unsigned* __restrict__ histDM, int shift) {
  __shared__ unsigned h[NDIG];
  int t = threadIdx.x;
  h[t] = 0;
  __syncthreads();
  int base = blockIdx.x * SCHUNK;
#pragma unroll
  for (int it = 0; it < SCHUNK / 256; ++it) {
    int i = base + it * 256 + t;
    if (i < n) atomicAdd(&h[(unsigned)(kp[i] >> (32 + shift)) & 255u], 1u);
  }
  __syncthreads();
  histDM[t * NB + blockIdx.x] = h[t];
}

__global__ void scan_rows(unsigned* __restrict__ histDM, unsigned* __restrict__ rowsum) {
  __shared__ unsigned lds[512];
  int d = blockIdx.x, t = threadIdx.x;
  unsigned v = (t < NB) ? histDM[d * NB + t] : 0u;
  lds[t] = v;
  __syncthreads();
#pragma unroll
  for (int off = 1; off < 512; off <<= 1) {
    unsigned add = (t >= off) ? lds[t - off] : 0u;
    __syncthreads();
    lds[t] += add;
    __syncthreads();
  }
  if (t < NB) histDM[d * NB + t] = lds[t] - v;
  if (t == 511) rowsum[d] = lds[511];
}

__global__ __launch_bounds__(STHREADS) void radix_scatter(
    const u64* __restrict__ kpin, int n,
    const unsigned* __restrict__ histDM, const unsigned* __restrict__ rowsum,
    u64* __restrict__ kpout, int shift) {
  __shared__ unsigned short whist[SIPT][NWAVE][NDIG];
  __shared__ unsigned goff[NDIG];
  __shared__ unsigned bexcl[NDIG];
  __shared__ unsigned scanbuf[NDIG];
  __shared__ u64 lkp[SCHUNK];
  int t = threadIdx.x, b = blockIdx.x;
  int wave = t >> 6, lane = t & 63;
  for (int j = t; j < SIPT * NWAVE * NDIG; j += STHREADS)
    ((unsigned short*)whist)[j] = 0;
  unsigned rs = rowsum[t];
  scanbuf[t] = rs;
  __syncthreads();
#pragma unroll
  for (int o = 1; o < NDIG; o <<= 1) {
    unsigned add = (t >= o) ? scanbuf[t - o] : 0u;
    __syncthreads();
    scanbuf[t] += add;
    __syncthreads();
  }
  goff[t] = (scanbuf[t] - rs) + histDM[t * NB + b];
  __syncthreads();

  u64 k[SIPT];
  unsigned dg[SIPT], lr[SIPT];
  bool val[SIPT];
  int base = b * SCHUNK;
#pragma unroll
  for (int s = 0; s < SIPT; ++s) {
    int i = base + s * STHREADS + t;
    val[s] = (i < n);
    k[s] = val[s] ? kpin[i] : 0ull;
    dg[s] = (unsigned)(k[s] >> (32 + shift)) & 255u;
  }
#pragma unroll
  for (int s = 0; s < SIPT; ++s) {
    unsigned long long m = ~0ull;
#pragma unroll
    for (int bb = 0; bb < 8; ++bb) {
      unsigned long long vote = __ballot((dg[s] >> bb) & 1u);
      m &= ((dg[s] >> bb) & 1u) ? vote : ~vote;
    }
    m &= __ballot(val[s]);
    lr[s] = (unsigned)__popcll(m & ((1ull << lane) - 1ull));
    if (val[s] && lr[s] == 0)
      whist[s][wave][dg[s]] = (unsigned short)__popcll(m);
  }
  __syncthreads();
  unsigned run = 0;
#pragma unroll
  for (int s = 0; s < SIPT; ++s)
#pragma unroll
    for (int w = 0; w < NWAVE; ++w) {
      unsigned c = whist[s][w][t];
      whist[s][w][t] = (unsigned short)run;
      run += c;
    }
  scanbuf[t] = run;
  __syncthreads();
#pragma unroll
  for (int o = 1; o < NDIG; o <<= 1) {
    unsigned add = (t >= o) ? scanbuf[t - o] : 0u;
    __syncthreads();
    scanbuf[t] += add;
    __syncthreads();
  }
  bexcl[t] = scanbuf[t] - run;
  __syncthreads();
#pragma unroll
  for (int s = 0; s < SIPT; ++s) {
    if (val[s]) {
      unsigned lp = bexcl[dg[s]] + (unsigned)whist[s][wave][dg[s]] + lr[s];
      lkp[lp] = k[s];
    }
  }
  __syncthreads();
  int nvalid = min(n - base, SCHUNK);
#pragma unroll
  for (int s = 0; s < SIPT; ++s) {
    int j = s * STHREADS + t;
    if (j < nvalid) {
      u64 kk = lkp[j];
      unsigned d = (unsigned)(kk >> (32 + shift)) & 255u;
      kpout[goff[d] + ((unsigned)j - bexcl[d])] = kk;
    }
  }
}

__global__ void init_kernel(int* __restrict__ ni, unsigned* __restrict__ bm, int n) {
  int i = blockIdx.x * blockDim.x + threadIdx.x;
  if (i < n) ni[i] = -1;
  if (i < BM_ALLOC) bm[i] = 0u;
}

__global__ void select_kernel(const u64* __restrict__ kp, const float* __restrict__ score,
                              const float* __restrict__ x, int* __restrict__ ni,
                              unsigned* __restrict__ bm, float* __restrict__ xout, int k) {
  int i = blockIdx.x * blockDim.x + threadIdx.x;
  if (i >= k) return;
  int pidx = (int)(unsigned)(kp[i] & 0xFFFFFFFFull);
  ni[pidx] = i;
  atomicOr(&bm[pidx >> 5], 1u << (pidx & 31));
  float s = score[pidx];
  xout[3*i+0] = __fmul_rn(x[3*pidx+0], s);
  xout[3*i+1] = __fmul_rn(x[3*pidx+1], s);
  xout[3*i+2] = __fmul_rn(x[3*pidx+2], s);
}

// ========================= edge relabel kernels ============================
// Big-LDS path: full 122KB bitmap staged once per persistent block; no
// barriers in the main loop.
__global__ __launch_bounds__(EB_THREADS) void edge_big(
    const int* __restrict__ ei, const int* __restrict__ ni,
    const unsigned* __restrict__ bm,
    float* __restrict__ oedge, float* __restrict__ omask) {
  extern __shared__ unsigned lbm[];
  for (int j = threadIdx.x; j < BM_ALLOC / 4; j += EB_THREADS)
    ((v4u*)lbm)[j] = ((const v4u*)bm)[j];
  __syncthreads();
  for (int c = blockIdx.x; c < NCHUNK; c += gridDim.x) {
    long long e = (long long)c * EB_EDGES + (long long)threadIdx.x * 8;
    if (e + 8 > (long long)N_EDGES) continue;  // N_EDGES%8==0 -> all-or-none
    v4i a0 = __builtin_nontemporal_load((const v4i*)(ei + e));
    v4i a1 = __builtin_nontemporal_load((const v4i*)(ei + e) + 1);
    v4i b0 = __builtin_nontemporal_load((const v4i*)(ei + (long long)N_EDGES + e));
    v4i b1 = __builtin_nontemporal_load((const v4i*)(ei + (long long)N_EDGES + e) + 1);
    int A[8], B[8];
#pragma unroll
    for (int j = 0; j < 4; ++j) {
      A[j] = a0[j]; A[4 + j] = a1[j];
      B[j] = b0[j]; B[4 + j] = b1[j];
    }
    unsigned mA = 0, mB = 0;
#pragma unroll
    for (int j = 0; j < 8; ++j) {
      mA |= ((lbm[A[j] >> 5] >> (A[j] & 31)) & 1u) << j;
      mB |= ((lbm[B[j] >> 5] >> (B[j] & 31)) & 1u) << j;
    }
    unsigned mm = mA & mB;
    float fa[8], fb[8], fm[8];
#pragma unroll
    for (int j = 0; j < 8; ++j) {
      bool m = (mm >> j) & 1u;
      int na = -1, nb = -1;
      if (m) { na = ni[A[j]]; nb = ni[B[j]]; }
      fa[j] = m ? (float)na : -1.0f;
      fb[j] = m ? (float)nb : -1.0f;
      fm[j] = m ? 1.0f : 0.0f;
    }
    __builtin_nontemporal_store(*(const v4f*)&fa[0], (v4f*)(oedge + e));
    __builtin_nontemporal_store(*(const v4f*)&fa[4], (v4f*)(oedge + e) + 1);
    __builtin_nontemporal_store(*(const v4f*)&fb[0], (v4f*)(oedge + (long long)N_EDGES + e));
    __builtin_nontemporal_store(*(const v4f*)&fb[4], (v4f*)(oedge + (long long)N_EDGES + e) + 1);
    __builtin_nontemporal_store(*(const v4f*)&fm[0], (v4f*)(omask + e));
    __builtin_nontemporal_store(*(const v4f*)&fm[4], (v4f*)(omask + e) + 1);
  }
}

// Fallback: two-phase 64KB static-LDS version (validated round 3).
__global__ __launch_bounds__(EB_THREADS) void edge_kernel(
    const int* __restrict__ ei, const int* __restrict__ ni,
    const unsigned* __restrict__ bm,
    float* __restrict__ oedge, float* __restrict__ omask) {
  __shared__ unsigned lbm[BM_W0];  // 64 KiB
  int t = threadIdx.x;
  long long e = (long long)blockIdx.x * EB_EDGES + (long long)t * 8;
  bool act = (e + 8 <= (long long)N_EDGES);

  v4i a0{}, a1{}, b0{}, b1{};
  if (act) {
    a0 = __builtin_nontemporal_load((const v4i*)(ei + e));
    a1 = __builtin_nontemporal_load((const v4i*)(ei + e) + 1);
    b0 = __builtin_nontemporal_load((const v4i*)(ei + (long long)N_EDGES + e));
    b1 = __builtin_nontemporal_load((const v4i*)(ei + (long long)N_EDGES + e) + 1);
  }
  int A[8], B[8];
#pragma unroll
  for (int j = 0; j < 4; ++j) {
    A[j] = a0[j]; A[4 + j] = a1[j];
    B[j] = b0[j]; B[4 + j] = b1[j];
  }
#pragma unroll
  for (int j = 0; j < BM_W0 / (EB_THREADS * 4); ++j)
    ((v4u*)lbm)[t + j * EB_THREADS] = ((const v4u*)bm)[t + j * EB_THREADS];
  __syncthreads();
  unsigned bA = 0, bB = 0;
  if (act) {
#pragma unroll
    for (int j = 0; j < 8; ++j) {
      if (A[j] < NODE_SPLIT) bA |= ((lbm[A[j] >> 5] >> (A[j] & 31)) & 1u) << j;
      if (B[j] < NODE_SPLIT) bB |= ((lbm[B[j] >> 5] >> (B[j] & 31)) & 1u) << j;
    }
  }
  __syncthreads();
  {
    const v4u* src = (const v4u*)(bm + BM_W0);
    for (int j = t; j < (BM_W1 + 3) / 4; j += EB_THREADS)
      ((v4u*)lbm)[j] = src[j];
  }
  __syncthreads();
  if (act) {
#pragma unroll
    for (int j = 0; j < 8; ++j) {
      if (A[j] >= NODE_SPLIT) {
        int q = A[j] - NODE_SPLIT;
        bA |= ((lbm[q >> 5] >> (q & 31)) & 1u) << j;
      }
      if (B[j] >= NODE_SPLIT) {
        int q = B[j] - NODE_SPLIT;
        bB |= ((lbm[q >> 5] >> (q & 31)) & 1u) << j;
      }
    }
    unsigned mm = bA & bB;
    float fa[8], fb[8], fm[8];
#pragma unroll
    for (int j = 0; j < 8; ++j) {
      bool m = (mm >> j) & 1u;
      int na = -1, nb = -1;
      if (m) { na = ni[A[j]]; nb = ni[B[j]]; }
      fa[j] = m ? (float)na : -1.0f;
      fb[j] = m ? (float)nb : -1.0f;
      fm[j] = m ? 1.0f : 0.0f;
    }
    __builtin_nontemporal_store(*(const v4f*)&fa[0], (v4f*)(oedge + e));
    __builtin_nontemporal_store(*(const v4f*)&fa[4], (v4f*)(oedge + e) + 1);
    __builtin_nontemporal_store(*(const v4f*)&fb[0], (v4f*)(oedge + (long long)N_EDGES + e));
    __builtin_nontemporal_store(*(const v4f*)&fb[4], (v4f*)(oedge + (long long)N_EDGES + e) + 1);
    __builtin_nontemporal_store(*(const v4f*)&fm[0], (v4f*)(omask + e));
    __builtin_nontemporal_store(*(const v4f*)&fm[4], (v4f*)(omask + e) + 1);
  }
}

extern "C" void kernel_launch(void* const* d_in, const int* in_sizes, int n_in,
                              void* d_out, int out_size, void* d_ws, size_t ws_size,
                              hipStream_t stream) {
  const float* x  = (const float*)d_in[0];
  const int*   ei = (const int*)d_in[1];
  const float* w  = (const float*)d_in[2];
  float* out = (float*)d_out;

  char* ws = (char*)d_ws;
  size_t off = 0;
  auto alloc = [&](size_t bytes) -> void* {
    void* ptr = ws + off;
    off += (bytes + 255) & ~size_t(255);
    return ptr;
  };
  float*    score  = (float*)alloc((size_t)N_NODES * 4);
  u64*      kp0    = (u64*)alloc((size_t)N_NODES * 8);
  u64*      kp1    = (u64*)alloc((size_t)N_NODES * 8);
  unsigned* histDM = (unsigned*)alloc((size_t)NDIG * NB * 4);
  unsigned* rowsum = (unsigned*)alloc((size_t)NDIG * 4);
  int*      ni     = (int*)alloc((size_t)N_NODES * 4);
  unsigned* bm     = (unsigned*)alloc((size_t)BM_ALLOC * 4);
  (void)ws_size; (void)in_sizes; (void)n_in; (void)out_size;

  // ---- fused cooperative path (score + sort + select) ----
  void* kargs[] = {(void*)&x, (void*)&w, (void*)&score, (void*)&kp0, (void*)&kp1,
                   (void*)&histDM, (void*)&rowsum, (void*)&ni, (void*)&bm, (void*)&out};
  hipError_t ce = hipLaunchCooperativeKernel((const void*)topk_coop, dim3(NB),
                                             dim3(STHREADS), kargs, 0, stream);
  if (ce != hipSuccess) {
    // fallback: validated multi-kernel path
    score_kernel<<<(N_NODES + 255) / 256, 256, 0, stream>>>(x, w, score, kp0, N_NODES);
    u64* kb[2] = {kp0, kp1};
    int cur = 0;
    for (int pass = 0; pass < 4; ++pass) {
      int shift = pass * 8;
      radix_hist   <<<NB,   256, 0, stream>>>(kb[cur], N_NODES, histDM, shift);
      scan_rows    <<<NDIG, 512, 0, stream>>>(histDM, rowsum);
      radix_scatter<<<NB, STHREADS, 0, stream>>>(kb[cur], N_NODES, histDM, rowsum,
                                                 kb[cur ^ 1], shift);
      cur ^= 1;
    }
    init_kernel  <<<(N_NODES + 255) / 256, 256, 0, stream>>>(ni, bm, N_NODES);
    select_kernel<<<(K_SEL + 255) / 256, 256, 0, stream>>>(kb[cur], score, x, ni, bm, out, K_SEL);
  }

  // ---- edge relabel: big-LDS persistent path with guarded fallback ----
  int dev = 0;
  hipGetDevice(&dev);
  int maxShm = 0;
  hipDeviceGetAttribute(&maxShm, hipDeviceAttributeMaxSharedMemoryPerMultiprocessor, dev);
  size_t need = (size_t)BM_ALLOC * 4;  // 125056 B
  bool big = false;
  if ((size_t)maxShm >= need) {
    if (hipFuncSetAttribute((const void*)edge_big,
                            hipFuncAttributeMaxDynamicSharedMemorySize,
                            (int)need) == hipSuccess)
      big = true;
  }
  if (big) {
    edge_big<<<256, EB_THREADS, need, stream>>>(ei, ni, bm,
                                                out + 1500000, out + 33500000);
  } else {
    edge_kernel<<<(N_EDGES + EB_EDGES - 1) / EB_EDGES, EB_THREADS, 0, stream>>>(
        ei, ni, bm, out + 1500000, out + 33500000);
  }
}